// Round 4
// baseline (482.485 us; speedup 1.0000x reference)
//
#include <hip/hip_runtime.h>
#include <hip/hip_bf16.h>

#define N_NODES 100000
#define N_EDGES 800000
#define D 128
#define K2 256     // concat [mean | x] K dimension
#define MT 32      // nodes per block in layer kernel

typedef __attribute__((ext_vector_type(8))) short bf16x8;
typedef __attribute__((ext_vector_type(4))) float f32x4;

__device__ __forceinline__ unsigned short f2bf(float f) {
    union { float f; unsigned u; } c; c.f = f;
    unsigned u = c.u;
    return (unsigned short)((u + 0x7fffu + ((u >> 16) & 1u)) >> 16);
}
__device__ __forceinline__ float bflo(unsigned u) {
    union { unsigned u; float f; } c; c.u = u << 16; return c.f;
}
__device__ __forceinline__ float bfhi(unsigned u) {
    union { unsigned u; float f; } c; c.u = u & 0xffff0000u; return c.f;
}

// ================= CSR build =================

__global__ __launch_bounds__(256) void hist_kernel(
    const int* __restrict__ dst, int* __restrict__ cnt)
{
    int e = blockIdx.x * blockDim.x + threadIdx.x;
    if (e < N_EDGES) atomicAdd(&cnt[dst[e]], 1);
}

__global__ __launch_bounds__(256) void scan_reduce(
    const int* __restrict__ degi, int* __restrict__ bsum)
{
    __shared__ int sh[256];
    int t = threadIdx.x;
    int i = blockIdx.x * 256 + t;
    sh[t] = (i < N_NODES) ? degi[i] : 0;
    __syncthreads();
    for (int off = 128; off >= 1; off >>= 1) {
        if (t < off) sh[t] += sh[t + off];
        __syncthreads();
    }
    if (t == 0) bsum[blockIdx.x] = sh[0];
}

__global__ __launch_bounds__(512) void scan_bsums(
    const int* __restrict__ bsum, int* __restrict__ boff, int nb)
{
    __shared__ int sh[512];
    int t = threadIdx.x;
    int v = (t < nb) ? bsum[t] : 0;
    sh[t] = v;
    __syncthreads();
    for (int off = 1; off < 512; off <<= 1) {
        int add = (t >= off) ? sh[t - off] : 0;
        __syncthreads();
        sh[t] += add;
        __syncthreads();
    }
    if (t < nb) boff[t] = sh[t] - v;
}

__global__ __launch_bounds__(256) void scan_write(
    const int* __restrict__ degi, const int* __restrict__ boff,
    int* __restrict__ row_ptr)
{
    __shared__ int sh[256];
    int t = threadIdx.x;
    int i = blockIdx.x * 256 + t;
    int v = (i < N_NODES) ? degi[i] : 0;
    sh[t] = v;
    __syncthreads();
    for (int off = 1; off < 256; off <<= 1) {
        int add = (t >= off) ? sh[t - off] : 0;
        __syncthreads();
        sh[t] += add;
        __syncthreads();
    }
    if (i < N_NODES) row_ptr[i] = boff[blockIdx.x] + sh[t] - v;
    if (blockIdx.x == 0 && t == 0) row_ptr[N_NODES] = N_EDGES;
}

__global__ __launch_bounds__(256) void fill_kernel(
    const int* __restrict__ src, const int* __restrict__ dst,
    const int* __restrict__ row_ptr, int* __restrict__ cnt,
    int* __restrict__ esrc)
{
    int e = blockIdx.x * blockDim.x + threadIdx.x;
    if (e < N_EDGES) {
        int d = dst[e];
        int p = row_ptr[d] + atomicAdd(&cnt[d], 1);
        esrc[p] = src[e];
    }
}

// ============ weight pre-convert: Wb[layer][j][k] = bf16([Wl | Wr]) ============
__global__ __launch_bounds__(256) void wconv_kernel(
    const float* __restrict__ Wl, const float* __restrict__ Wr,
    unsigned short* __restrict__ Wb)
{
    int idx = blockIdx.x * 256 + threadIdx.x;
    if (idx >= 3 * D * K2) return;
    int layer = idx / (D * K2);
    int rem = idx % (D * K2);
    int j = rem / K2;
    int k = rem % K2;
    float v = (k < D) ? Wl[(size_t)layer * D * D + j * D + k]
                      : Wr[(size_t)layer * D * D + j * D + (k - D)];
    Wb[idx] = f2bf(v);
}

// ============ x0 fp32 -> bf16 ============
__global__ __launch_bounds__(256) void xconv_kernel(
    const float* __restrict__ x, unsigned short* __restrict__ xb)
{
    int idx = blockIdx.x * 256 + threadIdx.x;   // N*D/4 float4s
    if (idx >= N_NODES * D / 4) return;
    float4 v = ((const float4*)x)[idx];
    ushort4 b;
    b.x = f2bf(v.x); b.y = f2bf(v.y); b.z = f2bf(v.z); b.w = f2bf(v.w);
    ((ushort4*)xb)[idx] = b;
}

// ===== layer: gather-mean + h=[mean|x]@Wb^T+bl; LN; ReLU; +res =====
// block = 256 threads (4 waves), MT=32 nodes.
__global__ __launch_bounds__(256) void layer_kernel(
    const unsigned short* __restrict__ xb,   // [N][128] bf16 activations in
    const int* __restrict__ rp,              // [N+1]
    const int* __restrict__ esrc,            // [E] CSR src lists per dst
    const unsigned short* __restrict__ Wb,   // [D][K2] bf16, this layer
    const float* __restrict__ bl,
    const float* __restrict__ gamma_,
    const float* __restrict__ beta_,
    unsigned short* __restrict__ xb_out,     // bf16 out (when !last)
    float* __restrict__ out_f32,             // fp32 out (when last)
    int addResidual, int last)
{
    __shared__ unsigned short a_lds[MT * K2];   // 16 KB, XOR-swizzled
    __shared__ float h_s[MT][D + 1];            // 16.5 KB
    __shared__ float mu_s[MT], rs_s[MT];

    int t = threadIdx.x;
    int w = t >> 6;
    int lane = t & 63;
    int base = blockIdx.x * MT;

    // ---- stage own rows into cols 128..255 (bytes 256..511), swizzled ----
#pragma unroll
    for (int it = 0; it < 2; ++it) {
        int idx = it * 256 + t;
        int n = idx >> 4;            // row 0..31
        int c = idx & 15;            // 16B chunk 0..15
        int byte = (n * 512 + 256 + c * 16) ^ ((n & 7) << 4);
        *(int4*)((char*)a_lds + byte) =
            *(const int4*)((const char*)(xb + (size_t)(base + n) * D) + c * 16);
    }

    // ---- gather mean into cols 0..127: wave w owns nodes w*8..w*8+7 ----
    for (int q = 0; q < 8; ++q) {
        int nl = w * 8 + q;
        int node = base + nl;
        int beg = rp[node], end = rp[node + 1];
        float ax = 0.f, ay = 0.f;
        int i = beg;
        for (; i + 4 <= end; i += 4) {
            int s0 = esrc[i], s1 = esrc[i + 1], s2 = esrc[i + 2], s3 = esrc[i + 3];
            unsigned u0 = *(const unsigned*)(xb + (size_t)s0 * D + lane * 2);
            unsigned u1 = *(const unsigned*)(xb + (size_t)s1 * D + lane * 2);
            unsigned u2 = *(const unsigned*)(xb + (size_t)s2 * D + lane * 2);
            unsigned u3 = *(const unsigned*)(xb + (size_t)s3 * D + lane * 2);
            ax += bflo(u0) + bflo(u1) + bflo(u2) + bflo(u3);
            ay += bfhi(u0) + bfhi(u1) + bfhi(u2) + bfhi(u3);
        }
        for (; i < end; ++i) {
            unsigned u = *(const unsigned*)(xb + (size_t)esrc[i] * D + lane * 2);
            ax += bflo(u); ay += bfhi(u);
        }
        float sc = 1.0f / fmaxf((float)(end - beg), 1.0f);
        unsigned pk = (unsigned)f2bf(ax * sc) | ((unsigned)f2bf(ay * sc) << 16);
        int byte = (nl * 512 + lane * 4) ^ ((nl & 7) << 4);
        *(unsigned*)((char*)a_lds + byte) = pk;
    }
    __syncthreads();

    // ---- MFMA: wave w owns rows (w>>1)*16..+16, cols (w&1)*64..+64 ----
    int lm = lane & 15;
    int lg = lane >> 4;
    int rowBase = (w >> 1) * 16;
    int colBase = (w & 1) * 64;

    f32x4 acc[4];
#pragma unroll
    for (int c = 0; c < 4; ++c) acc[c] = (f32x4){0.f, 0.f, 0.f, 0.f};

    int arow = rowBase + lm;
    int lin = arow * 512 + lg * 16;
    int swz = (arow & 7) << 4;
    const unsigned short* Bp = Wb + (size_t)(colBase + lm) * K2 + lg * 8;
    const char* aB = (const char*)a_lds;

#pragma unroll
    for (int ks = 0; ks < 8; ++ks) {
        bf16x8 a  = *(const bf16x8*)(aB + ((lin + ks * 64) ^ swz));
        bf16x8 b0 = *(const bf16x8*)(Bp + 0 * 16 * K2 + ks * 32);
        bf16x8 b1 = *(const bf16x8*)(Bp + 1 * 16 * K2 + ks * 32);
        bf16x8 b2 = *(const bf16x8*)(Bp + 2 * 16 * K2 + ks * 32);
        bf16x8 b3 = *(const bf16x8*)(Bp + 3 * 16 * K2 + ks * 32);
        acc[0] = __builtin_amdgcn_mfma_f32_16x16x32_bf16(a, b0, acc[0], 0, 0, 0);
        acc[1] = __builtin_amdgcn_mfma_f32_16x16x32_bf16(a, b1, acc[1], 0, 0, 0);
        acc[2] = __builtin_amdgcn_mfma_f32_16x16x32_bf16(a, b2, acc[2], 0, 0, 0);
        acc[3] = __builtin_amdgcn_mfma_f32_16x16x32_bf16(a, b3, acc[3], 0, 0, 0);
    }

    // ---- h + bias to LDS (D layout: col=lane&15, row=lg*4+reg) ----
    float blv[4];
#pragma unroll
    for (int c = 0; c < 4; ++c) blv[c] = bl[colBase + c * 16 + lm];
#pragma unroll
    for (int c = 0; c < 4; ++c)
#pragma unroll
        for (int r = 0; r < 4; ++r)
            h_s[rowBase + lg * 4 + r][colBase + c * 16 + lm] = acc[c][r] + blv[c];
    __syncthreads();

    // ---- LN stats: 8 threads per row ----
    {
        int n = t >> 3, r = t & 7;
        float s = 0.f, ss = 0.f;
#pragma unroll
        for (int i = 0; i < 16; ++i) {
            float v = h_s[n][r + i * 8];
            s += v; ss += v * v;
        }
#pragma unroll
        for (int m = 4; m >= 1; m >>= 1) {
            s  += __shfl_xor(s,  m, 8);
            ss += __shfl_xor(ss, m, 8);
        }
        if (r == 0) {
            float mu = s * (1.f / 128.f);
            float var = ss * (1.f / 128.f) - mu * mu;
            mu_s[n] = mu;
            rs_s[n] = rsqrtf(var + 1e-5f);
        }
    }
    __syncthreads();

    // ---- normalize + relu + residual (from LDS bf16 x) + write ----
#pragma unroll
    for (int it = 0; it < 16; ++it) {
        int idx = it * 256 + t;
        int n = idx >> 7, jj = idx & 127;
        int node = base + n;
        float v = (h_s[n][jj] - mu_s[n]) * rs_s[n] * gamma_[jj] + beta_[jj];
        v = fmaxf(v, 0.f);
        if (addResidual) {
            int byte = (n * 512 + 256 + jj * 2) ^ ((n & 7) << 4);
            unsigned short xu = *(const unsigned short*)((const char*)a_lds + byte);
            union { unsigned u; float f; } c; c.u = ((unsigned)xu) << 16;
            v += c.f;
        }
        if (last) out_f32[(size_t)node * D + jj] = v;
        else      xb_out[(size_t)node * D + jj] = f2bf(v);
    }
}

extern "C" void kernel_launch(void* const* d_in, const int* in_sizes, int n_in,
                              void* d_out, int out_size, void* d_ws, size_t ws_size,
                              hipStream_t stream) {
    const float* x0  = (const float*)d_in[0];
    const int*   ei  = (const int*)d_in[1];
    const float* Wl  = (const float*)d_in[2];
    const float* bl  = (const float*)d_in[3];
    const float* Wr  = (const float*)d_in[4];
    const float* gam = (const float*)d_in[5];
    const float* bet = (const float*)d_in[6];
    float* out = (float*)d_out;

    const int* src = ei;
    const int* dst = ei + N_EDGES;

    // ---- workspace layout ----
    int* rp   = (int*)d_ws;            // 100352 ints
    int* cnt  = rp + 100352;           // 100352 ints (dead after fill -> Wb)
    int* bsum = cnt + 100352;          // 512
    int* boff = bsum + 512;            // 512
    int* esrc = boff + 512;            // 800000
    unsigned short* xb0 = (unsigned short*)(esrc + 800000);  // N*D bf16 (25.6 MB)
    unsigned short* xb1 = xb0 + (size_t)N_NODES * D;         // N*D bf16 (25.6 MB)
    unsigned short* Wb  = (unsigned short*)cnt;              // 3*128*256 bf16 = 192 KB

    const int nbScan = (N_NODES + 255) / 256;
    const int nbEdge = (N_EDGES + 255) / 256;
    const int layerBlocks = N_NODES / MT;       // 3125

    // ---- CSR build ----
    hipMemsetAsync(cnt, 0, N_NODES * sizeof(int), stream);
    hist_kernel<<<nbEdge, 256, 0, stream>>>(dst, cnt);
    scan_reduce<<<nbScan, 256, 0, stream>>>(cnt, bsum);
    scan_bsums<<<1, 512, 0, stream>>>(bsum, boff, nbScan);
    scan_write<<<nbScan, 256, 0, stream>>>(cnt, boff, rp);
    hipMemsetAsync(cnt, 0, N_NODES * sizeof(int), stream);
    fill_kernel<<<nbEdge, 256, 0, stream>>>(src, dst, rp, cnt, esrc);

    // ---- weights -> bf16 (cnt dead now), x0 -> bf16 ----
    wconv_kernel<<<(3 * D * K2 + 255) / 256, 256, 0, stream>>>(Wl, Wr, Wb);
    xconv_kernel<<<(N_NODES * D / 4 + 255) / 256, 256, 0, stream>>>(x0, xb0);

    // ---- layer 0: xb0 -> xb1 ----
    layer_kernel<<<layerBlocks, 256, 0, stream>>>(
        xb0, rp, esrc, Wb, bl, gam, bet, xb1, out, 0, 0);

    // ---- layer 1: xb1 -> xb0 ----
    layer_kernel<<<layerBlocks, 256, 0, stream>>>(
        xb1, rp, esrc, Wb + D * K2, bl + D, gam + D, bet + D, xb0, out, 1, 0);

    // ---- layer 2: xb0 -> out (fp32) ----
    layer_kernel<<<layerBlocks, 256, 0, stream>>>(
        xb0, rp, esrc, Wb + 2 * D * K2, bl + 2 * D, gam + 2 * D, bet + 2 * D,
        xb1, out, 1, 1);
}

// Round 5
// 380.181 us; speedup vs baseline: 1.2691x; 1.2691x over previous
//
#include <hip/hip_runtime.h>
#include <hip/hip_bf16.h>

#define N_NODES 100000
#define N_EDGES 800000
#define D 128
#define K2 256     // concat [mean | x] K dimension
#define MT 32      // nodes per block in fused kernel

typedef __attribute__((ext_vector_type(8))) short bf16x8;
typedef __attribute__((ext_vector_type(4))) float f32x4;

__device__ __forceinline__ unsigned short f2bf(float f) {
    union { float f; unsigned u; } c; c.f = f;
    unsigned u = c.u;
    return (unsigned short)((u + 0x7fffu + ((u >> 16) & 1u)) >> 16);
}
__device__ __forceinline__ float bflo(unsigned u) {
    union { unsigned u; float f; } c; c.u = u << 16; return c.f;
}
__device__ __forceinline__ float bfhi(unsigned u) {
    union { unsigned u; float f; } c; c.u = u & 0xffff0000u; return c.f;
}

// ================= CSR build =================

__global__ __launch_bounds__(256) void hist_kernel(
    const int* __restrict__ dst, int* __restrict__ cnt)
{
    int e = blockIdx.x * blockDim.x + threadIdx.x;
    if (e < N_EDGES) atomicAdd(&cnt[dst[e]], 1);
}

__global__ __launch_bounds__(256) void scan_reduce(
    const int* __restrict__ degi, int* __restrict__ bsum)
{
    __shared__ int sh[256];
    int t = threadIdx.x;
    int i = blockIdx.x * 256 + t;
    sh[t] = (i < N_NODES) ? degi[i] : 0;
    __syncthreads();
    for (int off = 128; off >= 1; off >>= 1) {
        if (t < off) sh[t] += sh[t + off];
        __syncthreads();
    }
    if (t == 0) bsum[blockIdx.x] = sh[0];
}

__global__ __launch_bounds__(512) void scan_bsums(
    const int* __restrict__ bsum, int* __restrict__ boff, int nb)
{
    __shared__ int sh[512];
    int t = threadIdx.x;
    int v = (t < nb) ? bsum[t] : 0;
    sh[t] = v;
    __syncthreads();
    for (int off = 1; off < 512; off <<= 1) {
        int add = (t >= off) ? sh[t - off] : 0;
        __syncthreads();
        sh[t] += add;
        __syncthreads();
    }
    if (t < nb) boff[t] = sh[t] - v;
}

__global__ __launch_bounds__(256) void scan_write(
    const int* __restrict__ degi, const int* __restrict__ boff,
    int* __restrict__ row_ptr)
{
    __shared__ int sh[256];
    int t = threadIdx.x;
    int i = blockIdx.x * 256 + t;
    int v = (i < N_NODES) ? degi[i] : 0;
    sh[t] = v;
    __syncthreads();
    for (int off = 1; off < 256; off <<= 1) {
        int add = (t >= off) ? sh[t - off] : 0;
        __syncthreads();
        sh[t] += add;
        __syncthreads();
    }
    if (i < N_NODES) row_ptr[i] = boff[blockIdx.x] + sh[t] - v;
    if (blockIdx.x == 0 && t == 0) row_ptr[N_NODES] = N_EDGES;
}

__global__ __launch_bounds__(256) void fill_kernel(
    const int* __restrict__ src, const int* __restrict__ dst,
    const int* __restrict__ row_ptr, int* __restrict__ cnt,
    int* __restrict__ esrc)
{
    int e = blockIdx.x * blockDim.x + threadIdx.x;
    if (e < N_EDGES) {
        int d = dst[e];
        int p = row_ptr[d] + atomicAdd(&cnt[d], 1);
        esrc[p] = src[e];
    }
}

// ============ weight pre-convert: Wb[layer][j][k] = bf16([Wl | Wr]) ============
__global__ __launch_bounds__(256) void wconv_kernel(
    const float* __restrict__ Wl, const float* __restrict__ Wr,
    unsigned short* __restrict__ Wb)
{
    int idx = blockIdx.x * 256 + threadIdx.x;
    if (idx >= 3 * D * K2) return;
    int layer = idx / (D * K2);
    int rem = idx % (D * K2);
    int j = rem / K2;
    int k = rem % K2;
    float v = (k < D) ? Wl[(size_t)layer * D * D + j * D + k]
                      : Wr[(size_t)layer * D * D + j * D + (k - D)];
    Wb[idx] = f2bf(v);
}

// ============ x0 fp32 -> bf16 ============
__global__ __launch_bounds__(256) void xconv_kernel(
    const float* __restrict__ x, unsigned short* __restrict__ xb)
{
    int idx = blockIdx.x * 256 + threadIdx.x;
    if (idx >= N_NODES * D / 4) return;
    float4 v = ((const float4*)x)[idx];
    ushort4 b;
    b.x = f2bf(v.x); b.y = f2bf(v.y); b.z = f2bf(v.z); b.w = f2bf(v.w);
    ((ushort4*)xb)[idx] = b;
}

// ============ gather mean: 2 nodes per wave (32 lanes x 8B = 256B row) ============
__global__ __launch_bounds__(256) void agg_kernel(
    const unsigned short* __restrict__ xb, const int* __restrict__ rp,
    const int* __restrict__ esrc, unsigned short* __restrict__ meanb)
{
    int tid = blockIdx.x * 256 + threadIdx.x;
    int node = tid >> 5;
    int lane = tid & 31;
    if (node >= N_NODES) return;
    int beg = rp[node], end = rp[node + 1];
    float a0 = 0.f, a1 = 0.f, a2 = 0.f, a3 = 0.f;
    const unsigned short* xp = xb + lane * 4;
    int i = beg;
    for (; i + 4 <= end; i += 4) {
        int s0 = esrc[i], s1 = esrc[i + 1], s2 = esrc[i + 2], s3 = esrc[i + 3];
        uint2 u0 = *(const uint2*)(xp + (size_t)s0 * D);
        uint2 u1 = *(const uint2*)(xp + (size_t)s1 * D);
        uint2 u2 = *(const uint2*)(xp + (size_t)s2 * D);
        uint2 u3 = *(const uint2*)(xp + (size_t)s3 * D);
        a0 += bflo(u0.x) + bflo(u1.x) + bflo(u2.x) + bflo(u3.x);
        a1 += bfhi(u0.x) + bfhi(u1.x) + bfhi(u2.x) + bfhi(u3.x);
        a2 += bflo(u0.y) + bflo(u1.y) + bflo(u2.y) + bflo(u3.y);
        a3 += bfhi(u0.y) + bfhi(u1.y) + bfhi(u2.y) + bfhi(u3.y);
    }
    for (; i < end; ++i) {
        uint2 u = *(const uint2*)(xp + (size_t)esrc[i] * D);
        a0 += bflo(u.x); a1 += bfhi(u.x);
        a2 += bflo(u.y); a3 += bfhi(u.y);
    }
    float sc = 1.0f / fmaxf((float)(end - beg), 1.0f);
    unsigned p0 = (unsigned)f2bf(a0 * sc) | ((unsigned)f2bf(a1 * sc) << 16);
    unsigned p1 = (unsigned)f2bf(a2 * sc) | ((unsigned)f2bf(a3 * sc) << 16);
    *(uint2*)(meanb + (size_t)node * D + lane * 4) = make_uint2(p0, p1);
}

// ===== fused MFMA: h = [mean|x]@Wb^T + bl; LN; ReLU; +res =====
// block = 256 threads (4 waves), MT=32 nodes. meanb may alias the output buffer
// (each block reads only its own rows before writing them).
__global__ __launch_bounds__(256, 2) void fused_mfma_kernel(
    const unsigned short* __restrict__ xb,     // [N][D] bf16 layer input (residual)
    const unsigned short* __restrict__ meanb,  // [N][D] bf16 mean
    const unsigned short* __restrict__ Wb,     // [D][K2] bf16, this layer
    const float* __restrict__ bl,
    const float* __restrict__ gamma_,
    const float* __restrict__ beta_,
    unsigned short* __restrict__ xb_out,       // bf16 out (when !last)
    float* __restrict__ out_f32,               // fp32 out (when last)
    int addResidual, int last)
{
    __shared__ unsigned short a_lds[MT * K2];   // 16 KB, XOR-swizzled
    __shared__ float st_s[2][MT], st_ss[2][MT];
    __shared__ float mu_s[MT], rs_s[MT];

    int t = threadIdx.x;
    int w = t >> 6;
    int lane = t & 63;
    int lm = lane & 15;
    int lg = lane >> 4;
    int base = blockIdx.x * MT;
    int rowBase = (w >> 1) * 16;
    int colBase = (w & 1) * 64;

    // ---- preload ALL B fragments into registers (4 col-tiles x 8 ks) ----
    const unsigned short* Bp = Wb + (size_t)(colBase + lm) * K2 + lg * 8;
    bf16x8 breg[4][8];
#pragma unroll
    for (int c = 0; c < 4; ++c)
#pragma unroll
        for (int ks = 0; ks < 8; ++ks)
            breg[c][ks] = *(const bf16x8*)(Bp + c * 16 * K2 + ks * 32);

    // ---- stage mean -> bytes 0..255 per row, x -> bytes 256..511, swizzled ----
#pragma unroll
    for (int it = 0; it < 2; ++it) {
        int idx = it * 256 + t;
        int n = idx >> 4, c = idx & 15;
        int sw = (n & 7) << 4;
        *(int4*)((char*)a_lds + ((n * 512 + c * 16) ^ sw)) =
            *(const int4*)(meanb + (size_t)(base + n) * D + c * 8);
        *(int4*)((char*)a_lds + ((n * 512 + 256 + c * 16) ^ sw)) =
            *(const int4*)(xb + (size_t)(base + n) * D + c * 8);
    }
    __syncthreads();

    // ---- MFMA K-loop: pure ds_read + MFMA ----
    f32x4 acc[4];
#pragma unroll
    for (int c = 0; c < 4; ++c) acc[c] = (f32x4){0.f, 0.f, 0.f, 0.f};

    int arow = rowBase + lm;
    int lin = arow * 512 + lg * 16;
    int swz = (arow & 7) << 4;
    const char* aB = (const char*)a_lds;

#pragma unroll
    for (int ks = 0; ks < 8; ++ks) {
        bf16x8 a = *(const bf16x8*)(aB + ((lin + ks * 64) ^ swz));
        acc[0] = __builtin_amdgcn_mfma_f32_16x16x32_bf16(a, breg[0][ks], acc[0], 0, 0, 0);
        acc[1] = __builtin_amdgcn_mfma_f32_16x16x32_bf16(a, breg[1][ks], acc[1], 0, 0, 0);
        acc[2] = __builtin_amdgcn_mfma_f32_16x16x32_bf16(a, breg[2][ks], acc[2], 0, 0, 0);
        acc[3] = __builtin_amdgcn_mfma_f32_16x16x32_bf16(a, breg[3][ks], acc[3], 0, 0, 0);
    }

    // ---- bias + LN stats from accumulators (no h_s round-trip) ----
    float bw[4], gw[4], be[4];
#pragma unroll
    for (int c = 0; c < 4; ++c) {
        int col = colBase + c * 16 + lm;
        bw[c] = bl[col]; gw[c] = gamma_[col]; be[c] = beta_[col];
    }
    float s[4] = {0.f, 0.f, 0.f, 0.f}, ss[4] = {0.f, 0.f, 0.f, 0.f};
#pragma unroll
    for (int c = 0; c < 4; ++c)
#pragma unroll
        for (int r = 0; r < 4; ++r) {
            float v = acc[c][r] + bw[c];
            acc[c][r] = v;
            s[r] += v; ss[r] += v * v;
        }
#pragma unroll
    for (int r = 0; r < 4; ++r)
#pragma unroll
        for (int m = 1; m < 16; m <<= 1) {
            s[r]  += __shfl_xor(s[r],  m);
            ss[r] += __shfl_xor(ss[r], m);
        }
    if (lm == 0) {
#pragma unroll
        for (int r = 0; r < 4; ++r) {
            int R = rowBase + lg * 4 + r;
            st_s[w & 1][R]  = s[r];
            st_ss[w & 1][R] = ss[r];
        }
    }
    __syncthreads();
    if (t < MT) {
        float sum = st_s[0][t] + st_s[1][t];
        float sq  = st_ss[0][t] + st_ss[1][t];
        float mu = sum * (1.f / 128.f);
        float var = sq * (1.f / 128.f) - mu * mu;
        mu_s[t] = mu;
        rs_s[t] = rsqrtf(var + 1e-5f);
    }
    __syncthreads();

    // ---- normalize + relu + residual + direct store ----
#pragma unroll
    for (int r = 0; r < 4; ++r) {
        int R = rowBase + lg * 4 + r;
        float mu = mu_s[R], rs = rs_s[R];
        int node = base + R;
        int rsw = (R & 7) << 4;
#pragma unroll
        for (int c = 0; c < 4; ++c) {
            int col = colBase + c * 16 + lm;
            float v = (acc[c][r] - mu) * rs * gw[c] + be[c];
            v = fmaxf(v, 0.f);
            if (addResidual) {
                unsigned short xu = *(const unsigned short*)(
                    (const char*)a_lds + ((R * 512 + 256 + col * 2) ^ rsw));
                union { unsigned u; float f; } cv; cv.u = ((unsigned)xu) << 16;
                v += cv.f;
            }
            if (last) out_f32[(size_t)node * D + col] = v;
            else      xb_out[(size_t)node * D + col] = f2bf(v);
        }
    }
}

extern "C" void kernel_launch(void* const* d_in, const int* in_sizes, int n_in,
                              void* d_out, int out_size, void* d_ws, size_t ws_size,
                              hipStream_t stream) {
    const float* x0  = (const float*)d_in[0];
    const int*   ei  = (const int*)d_in[1];
    const float* Wl  = (const float*)d_in[2];
    const float* bl  = (const float*)d_in[3];
    const float* Wr  = (const float*)d_in[4];
    const float* gam = (const float*)d_in[5];
    const float* bet = (const float*)d_in[6];
    float* out = (float*)d_out;

    const int* src = ei;
    const int* dst = ei + N_EDGES;

    // ---- workspace layout ----
    int* rp   = (int*)d_ws;            // 100352 ints
    int* cnt  = rp + 100352;           // 100352 ints (dead after fill -> Wb)
    int* bsum = cnt + 100352;          // 512
    int* boff = bsum + 512;            // 512
    int* esrc = boff + 512;            // 800000
    unsigned short* xb0 = (unsigned short*)(esrc + 800000);  // N*D bf16 (25.6 MB)
    unsigned short* xb1 = xb0 + (size_t)N_NODES * D;         // N*D bf16 (25.6 MB)
    unsigned short* Wb  = (unsigned short*)cnt;              // 192 KB

    const int nbScan = (N_NODES + 255) / 256;
    const int nbEdge = (N_EDGES + 255) / 256;
    const int aggBlocks = (N_NODES * 32 + 255) / 256;   // 12500
    const int fusedBlocks = N_NODES / MT;               // 3125

    // ---- CSR build ----
    hipMemsetAsync(cnt, 0, N_NODES * sizeof(int), stream);
    hist_kernel<<<nbEdge, 256, 0, stream>>>(dst, cnt);
    scan_reduce<<<nbScan, 256, 0, stream>>>(cnt, bsum);
    scan_bsums<<<1, 512, 0, stream>>>(bsum, boff, nbScan);
    scan_write<<<nbScan, 256, 0, stream>>>(cnt, boff, rp);
    hipMemsetAsync(cnt, 0, N_NODES * sizeof(int), stream);
    fill_kernel<<<nbEdge, 256, 0, stream>>>(src, dst, rp, cnt, esrc);

    // ---- weights -> bf16 (cnt dead now), x0 -> bf16 ----
    wconv_kernel<<<(3 * D * K2 + 255) / 256, 256, 0, stream>>>(Wl, Wr, Wb);
    xconv_kernel<<<(N_NODES * D / 4 + 255) / 256, 256, 0, stream>>>(x0, xb0);

    // ---- layer 0: x=xb0, mean->xb1, out->xb1 ----
    agg_kernel<<<aggBlocks, 256, 0, stream>>>(xb0, rp, esrc, xb1);
    fused_mfma_kernel<<<fusedBlocks, 256, 0, stream>>>(
        xb0, xb1, Wb, bl, gam, bet, xb1, out, 0, 0);

    // ---- layer 1: x=xb1, mean->xb0, out->xb0 ----
    agg_kernel<<<aggBlocks, 256, 0, stream>>>(xb1, rp, esrc, xb0);
    fused_mfma_kernel<<<fusedBlocks, 256, 0, stream>>>(
        xb1, xb0, Wb + D * K2, bl + D, gam + D, bet + D, xb0, out, 1, 0);

    // ---- layer 2: x=xb0, mean->xb1, out->d_out (fp32) ----
    agg_kernel<<<aggBlocks, 256, 0, stream>>>(xb0, rp, esrc, xb1);
    fused_mfma_kernel<<<fusedBlocks, 256, 0, stream>>>(
        xb0, xb1, Wb + 2 * D * K2, bl + 2 * D, gam + 2 * D, bet + 2 * D,
        xb1, out, 1, 1);
}

// Round 6
// 345.204 us; speedup vs baseline: 1.3977x; 1.1013x over previous
//
#include <hip/hip_runtime.h>
#include <hip/hip_bf16.h>

#define N_NODES 100000
#define N_EDGES 800000
#define D 128
#define K2 256     // concat [mean | x] K dimension
#define MT 64      // nodes per block in fused kernel (2 row-tiles per wave)

typedef __attribute__((ext_vector_type(8))) short bf16x8;
typedef __attribute__((ext_vector_type(4))) float f32x4;

__device__ __forceinline__ unsigned short f2bf(float f) {
    union { float f; unsigned u; } c; c.f = f;
    unsigned u = c.u;
    return (unsigned short)((u + 0x7fffu + ((u >> 16) & 1u)) >> 16);
}
__device__ __forceinline__ float bflo(unsigned u) {
    union { unsigned u; float f; } c; c.u = u << 16; return c.f;
}
__device__ __forceinline__ float bfhi(unsigned u) {
    union { unsigned u; float f; } c; c.u = u & 0xffff0000u; return c.f;
}

// ================= CSR build =================

__global__ __launch_bounds__(256) void hist_kernel(
    const int* __restrict__ dst, int* __restrict__ cnt)
{
    int e = blockIdx.x * blockDim.x + threadIdx.x;
    if (e < N_EDGES) atomicAdd(&cnt[dst[e]], 1);
}

__global__ __launch_bounds__(256) void scan_reduce(
    const int* __restrict__ degi, int* __restrict__ bsum)
{
    __shared__ int sh[256];
    int t = threadIdx.x;
    int i = blockIdx.x * 256 + t;
    sh[t] = (i < N_NODES) ? degi[i] : 0;
    __syncthreads();
    for (int off = 128; off >= 1; off >>= 1) {
        if (t < off) sh[t] += sh[t + off];
        __syncthreads();
    }
    if (t == 0) bsum[blockIdx.x] = sh[0];
}

__global__ __launch_bounds__(512) void scan_bsums(
    const int* __restrict__ bsum, int* __restrict__ boff, int nb)
{
    __shared__ int sh[512];
    int t = threadIdx.x;
    int v = (t < nb) ? bsum[t] : 0;
    sh[t] = v;
    __syncthreads();
    for (int off = 1; off < 512; off <<= 1) {
        int add = (t >= off) ? sh[t - off] : 0;
        __syncthreads();
        sh[t] += add;
        __syncthreads();
    }
    if (t < nb) boff[t] = sh[t] - v;
}

__global__ __launch_bounds__(256) void scan_write(
    const int* __restrict__ degi, const int* __restrict__ boff,
    int* __restrict__ row_ptr)
{
    __shared__ int sh[256];
    int t = threadIdx.x;
    int i = blockIdx.x * 256 + t;
    int v = (i < N_NODES) ? degi[i] : 0;
    sh[t] = v;
    __syncthreads();
    for (int off = 1; off < 256; off <<= 1) {
        int add = (t >= off) ? sh[t - off] : 0;
        __syncthreads();
        sh[t] += add;
        __syncthreads();
    }
    if (i < N_NODES) row_ptr[i] = boff[blockIdx.x] + sh[t] - v;
    if (blockIdx.x == 0 && t == 0) row_ptr[N_NODES] = N_EDGES;
}

__global__ __launch_bounds__(256) void fill_kernel(
    const int* __restrict__ src, const int* __restrict__ dst,
    const int* __restrict__ row_ptr, int* __restrict__ cnt,
    int* __restrict__ esrc)
{
    int e = blockIdx.x * blockDim.x + threadIdx.x;
    if (e < N_EDGES) {
        int d = dst[e];
        int p = row_ptr[d] + atomicAdd(&cnt[d], 1);
        esrc[p] = src[e];
    }
}

// ============ weight pre-convert: Wb[layer][j][k] = bf16([Wl | Wr]) ============
__global__ __launch_bounds__(256) void wconv_kernel(
    const float* __restrict__ Wl, const float* __restrict__ Wr,
    unsigned short* __restrict__ Wb)
{
    int idx = blockIdx.x * 256 + threadIdx.x;
    if (idx >= 3 * D * K2) return;
    int layer = idx / (D * K2);
    int rem = idx % (D * K2);
    int j = rem / K2;
    int k = rem % K2;
    float v = (k < D) ? Wl[(size_t)layer * D * D + j * D + k]
                      : Wr[(size_t)layer * D * D + j * D + (k - D)];
    Wb[idx] = f2bf(v);
}

// ============ x0 fp32 -> bf16 ============
__global__ __launch_bounds__(256) void xconv_kernel(
    const float* __restrict__ x, unsigned short* __restrict__ xb)
{
    int idx = blockIdx.x * 256 + threadIdx.x;
    if (idx >= N_NODES * D / 4) return;
    float4 v = ((const float4*)x)[idx];
    ushort4 b;
    b.x = f2bf(v.x); b.y = f2bf(v.y); b.z = f2bf(v.z); b.w = f2bf(v.w);
    ((ushort4*)xb)[idx] = b;
}

// ============ gather mean: 2 nodes per wave (32 lanes x 8B = 256B row) ============
__global__ __launch_bounds__(256) void agg_kernel(
    const unsigned short* __restrict__ xb, const int* __restrict__ rp,
    const int* __restrict__ esrc, unsigned short* __restrict__ meanb)
{
    int tid = blockIdx.x * 256 + threadIdx.x;
    int node = tid >> 5;
    int lane = tid & 31;
    if (node >= N_NODES) return;
    int beg = rp[node], end = rp[node + 1];
    float a0 = 0.f, a1 = 0.f, a2 = 0.f, a3 = 0.f;
    const unsigned short* xp = xb + lane * 4;
    int i = beg;
    for (; i + 4 <= end; i += 4) {
        int s0 = esrc[i], s1 = esrc[i + 1], s2 = esrc[i + 2], s3 = esrc[i + 3];
        uint2 u0 = *(const uint2*)(xp + (size_t)s0 * D);
        uint2 u1 = *(const uint2*)(xp + (size_t)s1 * D);
        uint2 u2 = *(const uint2*)(xp + (size_t)s2 * D);
        uint2 u3 = *(const uint2*)(xp + (size_t)s3 * D);
        a0 += bflo(u0.x) + bflo(u1.x) + bflo(u2.x) + bflo(u3.x);
        a1 += bfhi(u0.x) + bfhi(u1.x) + bfhi(u2.x) + bfhi(u3.x);
        a2 += bflo(u0.y) + bflo(u1.y) + bflo(u2.y) + bflo(u3.y);
        a3 += bfhi(u0.y) + bfhi(u1.y) + bfhi(u2.y) + bfhi(u3.y);
    }
    for (; i < end; ++i) {
        uint2 u = *(const uint2*)(xp + (size_t)esrc[i] * D);
        a0 += bflo(u.x); a1 += bfhi(u.x);
        a2 += bflo(u.y); a3 += bfhi(u.y);
    }
    float sc = 1.0f / fmaxf((float)(end - beg), 1.0f);
    unsigned p0 = (unsigned)f2bf(a0 * sc) | ((unsigned)f2bf(a1 * sc) << 16);
    unsigned p1 = (unsigned)f2bf(a2 * sc) | ((unsigned)f2bf(a3 * sc) << 16);
    *(uint2*)(meanb + (size_t)node * D + lane * 4) = make_uint2(p0, p1);
}

// ===== fused MFMA: h = [mean|x]@Wb^T + bl; LN; ReLU; +res =====
// block = 256 threads (4 waves), MT=64 nodes; each wave: 2 row-tiles x 1 col-tile,
// B fragments register-resident and reused by both row-tiles.
// meanb may alias the output buffer (each block touches only its own rows).
__global__ __launch_bounds__(256, 2) void fused_mfma_kernel(
    const unsigned short* __restrict__ xb,     // [N][D] bf16 layer input (residual)
    const unsigned short* __restrict__ meanb,  // [N][D] bf16 mean
    const unsigned short* __restrict__ Wb,     // [D][K2] bf16, this layer
    const float* __restrict__ bl,
    const float* __restrict__ gamma_,
    const float* __restrict__ beta_,
    unsigned short* __restrict__ xb_out,       // bf16 out (when !last)
    float* __restrict__ out_f32,               // fp32 out (when last)
    int addResidual, int last)
{
    __shared__ unsigned short a_lds[MT * K2];   // 32 KB, XOR-swizzled
    __shared__ float st_s[2][MT], st_ss[2][MT];
    __shared__ float mu_s[MT], rs_s[MT];

    int t = threadIdx.x;
    int w = t >> 6;
    int lane = t & 63;
    int lm = lane & 15;
    int lg = lane >> 4;
    int base = blockIdx.x * MT;
    int rowBase = (w >> 1) * 16;     // tile0 rows; tile1 = +32
    int colBase = (w & 1) * 64;

    // ---- preload ALL B fragments into registers (4 col-tiles x 8 ks) ----
    const unsigned short* Bp = Wb + (size_t)(colBase + lm) * K2 + lg * 8;
    bf16x8 breg[4][8];
#pragma unroll
    for (int c = 0; c < 4; ++c)
#pragma unroll
        for (int ks = 0; ks < 8; ++ks)
            breg[c][ks] = *(const bf16x8*)(Bp + c * 16 * K2 + ks * 32);

    // ---- stage mean -> bytes 0..255 per row, x -> bytes 256..511, swizzled ----
#pragma unroll
    for (int it = 0; it < 4; ++it) {
        int idx = it * 256 + t;       // 0..1023
        int n = idx >> 4, c = idx & 15;
        int node = min(base + n, N_NODES - 1);
        int sw = (n & 7) << 4;
        *(int4*)((char*)a_lds + ((n * 512 + c * 16) ^ sw)) =
            *(const int4*)(meanb + (size_t)node * D + c * 8);
        *(int4*)((char*)a_lds + ((n * 512 + 256 + c * 16) ^ sw)) =
            *(const int4*)(xb + (size_t)node * D + c * 8);
    }
    __syncthreads();

    // ---- MFMA K-loop: pure ds_read + MFMA, two row-tiles share breg ----
    f32x4 acc0[4], acc1[4];
#pragma unroll
    for (int c = 0; c < 4; ++c) {
        acc0[c] = (f32x4){0.f, 0.f, 0.f, 0.f};
        acc1[c] = (f32x4){0.f, 0.f, 0.f, 0.f};
    }

    int r0 = rowBase + lm;
    int r1 = r0 + 32;                 // (r1&7)==(r0&7): same swizzle
    int lin0 = r0 * 512 + lg * 16;
    int lin1 = r1 * 512 + lg * 16;
    int swz = (r0 & 7) << 4;
    const char* aB = (const char*)a_lds;

#pragma unroll
    for (int ks = 0; ks < 8; ++ks) {
        bf16x8 a0 = *(const bf16x8*)(aB + ((lin0 + ks * 64) ^ swz));
        bf16x8 a1 = *(const bf16x8*)(aB + ((lin1 + ks * 64) ^ swz));
        acc0[0] = __builtin_amdgcn_mfma_f32_16x16x32_bf16(a0, breg[0][ks], acc0[0], 0, 0, 0);
        acc1[0] = __builtin_amdgcn_mfma_f32_16x16x32_bf16(a1, breg[0][ks], acc1[0], 0, 0, 0);
        acc0[1] = __builtin_amdgcn_mfma_f32_16x16x32_bf16(a0, breg[1][ks], acc0[1], 0, 0, 0);
        acc1[1] = __builtin_amdgcn_mfma_f32_16x16x32_bf16(a1, breg[1][ks], acc1[1], 0, 0, 0);
        acc0[2] = __builtin_amdgcn_mfma_f32_16x16x32_bf16(a0, breg[2][ks], acc0[2], 0, 0, 0);
        acc1[2] = __builtin_amdgcn_mfma_f32_16x16x32_bf16(a1, breg[2][ks], acc1[2], 0, 0, 0);
        acc0[3] = __builtin_amdgcn_mfma_f32_16x16x32_bf16(a0, breg[3][ks], acc0[3], 0, 0, 0);
        acc1[3] = __builtin_amdgcn_mfma_f32_16x16x32_bf16(a1, breg[3][ks], acc1[3], 0, 0, 0);
    }

    // ---- bias + LN partial stats from accumulators ----
    float bw[4], gw[4], be[4];
#pragma unroll
    for (int c = 0; c < 4; ++c) {
        int col = colBase + c * 16 + lm;
        bw[c] = bl[col]; gw[c] = gamma_[col]; be[c] = beta_[col];
    }
    float s0[4] = {0,0,0,0}, ss0[4] = {0,0,0,0};
    float s1[4] = {0,0,0,0}, ss1[4] = {0,0,0,0};
#pragma unroll
    for (int c = 0; c < 4; ++c)
#pragma unroll
        for (int r = 0; r < 4; ++r) {
            float v0 = acc0[c][r] + bw[c];
            float v1 = acc1[c][r] + bw[c];
            acc0[c][r] = v0; acc1[c][r] = v1;
            s0[r] += v0; ss0[r] += v0 * v0;
            s1[r] += v1; ss1[r] += v1 * v1;
        }
#pragma unroll
    for (int r = 0; r < 4; ++r)
#pragma unroll
        for (int m = 1; m < 16; m <<= 1) {
            s0[r]  += __shfl_xor(s0[r],  m);
            ss0[r] += __shfl_xor(ss0[r], m);
            s1[r]  += __shfl_xor(s1[r],  m);
            ss1[r] += __shfl_xor(ss1[r], m);
        }
    if (lm == 0) {
#pragma unroll
        for (int r = 0; r < 4; ++r) {
            int R = rowBase + lg * 4 + r;
            st_s[w & 1][R]       = s0[r];
            st_ss[w & 1][R]      = ss0[r];
            st_s[w & 1][R + 32]  = s1[r];
            st_ss[w & 1][R + 32] = ss1[r];
        }
    }
    __syncthreads();
    if (t < MT) {
        float sum = st_s[0][t] + st_s[1][t];
        float sq  = st_ss[0][t] + st_ss[1][t];
        float mu = sum * (1.f / 128.f);
        float var = sq * (1.f / 128.f) - mu * mu;
        mu_s[t] = mu;
        rs_s[t] = rsqrtf(var + 1e-5f);
    }
    __syncthreads();

    // ---- normalize + relu + residual + direct store (both tiles) ----
#pragma unroll
    for (int tile = 0; tile < 2; ++tile) {
#pragma unroll
        for (int r = 0; r < 4; ++r) {
            int R = rowBase + lg * 4 + r + tile * 32;
            int node = base + R;
            if (node >= N_NODES) continue;
            float mu = mu_s[R], rs = rs_s[R];
            int rsw = (R & 7) << 4;
#pragma unroll
            for (int c = 0; c < 4; ++c) {
                int col = colBase + c * 16 + lm;
                float av = tile ? acc1[c][r] : acc0[c][r];
                float v = (av - mu) * rs * gw[c] + be[c];
                v = fmaxf(v, 0.f);
                if (addResidual) {
                    unsigned short xu = *(const unsigned short*)(
                        (const char*)a_lds + ((R * 512 + 256 + col * 2) ^ rsw));
                    union { unsigned u; float f; } cv; cv.u = ((unsigned)xu) << 16;
                    v += cv.f;
                }
                if (last) out_f32[(size_t)node * D + col] = v;
                else      xb_out[(size_t)node * D + col] = f2bf(v);
            }
        }
    }
}

extern "C" void kernel_launch(void* const* d_in, const int* in_sizes, int n_in,
                              void* d_out, int out_size, void* d_ws, size_t ws_size,
                              hipStream_t stream) {
    const float* x0  = (const float*)d_in[0];
    const int*   ei  = (const int*)d_in[1];
    const float* Wl  = (const float*)d_in[2];
    const float* bl  = (const float*)d_in[3];
    const float* Wr  = (const float*)d_in[4];
    const float* gam = (const float*)d_in[5];
    const float* bet = (const float*)d_in[6];
    float* out = (float*)d_out;

    const int* src = ei;
    const int* dst = ei + N_EDGES;

    // ---- workspace layout ----
    int* rp   = (int*)d_ws;            // 100352 ints
    int* cnt  = rp + 100352;           // 100352 ints (dead after fill -> Wb)
    int* bsum = cnt + 100352;          // 512
    int* boff = bsum + 512;            // 512
    int* esrc = boff + 512;            // 800000
    unsigned short* xb0 = (unsigned short*)(esrc + 800000);  // N*D bf16 (25.6 MB)
    unsigned short* xb1 = xb0 + (size_t)N_NODES * D;         // N*D bf16 (25.6 MB)
    unsigned short* Wb  = (unsigned short*)cnt;              // 192 KB

    const int nbScan = (N_NODES + 255) / 256;
    const int nbEdge = (N_EDGES + 255) / 256;
    const int aggBlocks = (N_NODES * 32 + 255) / 256;       // 12500
    const int fusedBlocks = (N_NODES + MT - 1) / MT;        // 1563

    // ---- CSR build ----
    hipMemsetAsync(cnt, 0, N_NODES * sizeof(int), stream);
    hist_kernel<<<nbEdge, 256, 0, stream>>>(dst, cnt);
    scan_reduce<<<nbScan, 256, 0, stream>>>(cnt, bsum);
    scan_bsums<<<1, 512, 0, stream>>>(bsum, boff, nbScan);
    scan_write<<<nbScan, 256, 0, stream>>>(cnt, boff, rp);
    hipMemsetAsync(cnt, 0, N_NODES * sizeof(int), stream);
    fill_kernel<<<nbEdge, 256, 0, stream>>>(src, dst, rp, cnt, esrc);

    // ---- weights -> bf16 (cnt dead now), x0 -> bf16 ----
    wconv_kernel<<<(3 * D * K2 + 255) / 256, 256, 0, stream>>>(Wl, Wr, Wb);
    xconv_kernel<<<(N_NODES * D / 4 + 255) / 256, 256, 0, stream>>>(x0, xb0);

    // ---- layer 0: x=xb0, mean->xb1, out->xb1 ----
    agg_kernel<<<aggBlocks, 256, 0, stream>>>(xb0, rp, esrc, xb1);
    fused_mfma_kernel<<<fusedBlocks, 256, 0, stream>>>(
        xb0, xb1, Wb, bl, gam, bet, xb1, out, 0, 0);

    // ---- layer 1: x=xb1, mean->xb0, out->xb0 ----
    agg_kernel<<<aggBlocks, 256, 0, stream>>>(xb1, rp, esrc, xb0);
    fused_mfma_kernel<<<fusedBlocks, 256, 0, stream>>>(
        xb1, xb0, Wb + D * K2, bl + D, gam + D, bet + D, xb0, out, 1, 0);

    // ---- layer 2: x=xb0, mean->xb1, out->d_out (fp32) ----
    agg_kernel<<<aggBlocks, 256, 0, stream>>>(xb0, rp, esrc, xb1);
    fused_mfma_kernel<<<fusedBlocks, 256, 0, stream>>>(
        xb0, xb1, Wb + 2 * D * K2, bl + 2 * D, gam + 2 * D, bet + 2 * D,
        xb1, out, 1, 1);
}